// Round 2
// baseline (1238.020 us; speedup 1.0000x reference)
//
#include <hip/hip_runtime.h>

// Problem constants
static constexpr int Bn  = 64;     // batch
static constexpr int T   = 2048;   // angles
static constexpr int NA  = 256;    // atoms
static constexpr int DA  = 256;    // d_atom (K1)
static constexpr int DH  = 512;    // d_hid  (N1 / K2)
static constexpr int DO  = 256;    // d_out  (N2)
static constexpr int M   = Bn * T;         // 131072 rows
static constexpr int MT1 = M / 64;         // 2048 m-tiles of 64 rows

typedef __attribute__((ext_vector_type(4))) float  f32x4;
typedef __attribute__((ext_vector_type(8))) __bf16 bf16x8;
typedef __attribute__((ext_vector_type(8))) short  short8;
typedef __attribute__((ext_vector_type(4))) unsigned short ushort4v;

__device__ __forceinline__ unsigned short f2bf(float f) {
  union { float f; unsigned u; } v; v.f = f;
  unsigned u = v.u + 0x7FFFu + ((v.u >> 16) & 1u);   // RNE
  return (unsigned short)(u >> 16);
}
__device__ __forceinline__ float bf2f(unsigned short b) {
  union { unsigned u; float f; } v; v.u = ((unsigned)b) << 16;
  return v.f;
}

// ---------------------------------------------------------------------------
// prep: W1 [256x512] f32 -> W1T [512][256] bf16 ; W2 [512x256] f32 -> W2T [256][512] bf16
// ---------------------------------------------------------------------------
__global__ void prep_kernel(const float* __restrict__ W1, const float* __restrict__ W2,
                            unsigned short* __restrict__ W1T, unsigned short* __restrict__ W2T) {
  int id = blockIdx.x * 256 + threadIdx.x;           // 131072 threads
  {
    int n = id >> 8, k = id & 255;                   // W1T[n][k] = W1[k][n]
    W1T[id] = f2bf(W1[k * DH + n]);
  }
  {
    int n = id >> 9, k = id & 511;                   // W2T[n][k] = W2[k][n]
    W2T[id] = f2bf(W2[k * DO + n]);
  }
}

// ---------------------------------------------------------------------------
// k1: gather(z,idx) -> x[64 x 256] -> h = x@W1 + b1 (bf16, coalesced via LDS
// transpose) + column partial stats.
// grid: 2048 blocks (64-row tiles), 256 threads (4 waves).
// MFMA operands swapped: C row-dim = n (q*4+p), col-dim = m (r16) so each lane
// holds 4 n-contiguous values -> b64 LDS writes -> b128 reads -> dwordx4 store.
// ---------------------------------------------------------------------------
__global__ __launch_bounds__(256) void k1_gemm1(
    const float* __restrict__ z, const int* __restrict__ tbl,
    const unsigned short* __restrict__ W1T, const float* __restrict__ b1,
    unsigned short* __restrict__ hbuf, float* __restrict__ psum, float* __restrict__ psumsq) {
  __shared__ __align__(16) unsigned short As[64][40];      // m x k, +8 pad
  __shared__ __align__(16) unsigned short BsS[512 * 40];   // Bs[512][40] | S[64][136]
  __shared__ int idxs[64][3];
  unsigned short (*Bs)[40]  = (unsigned short (*)[40])BsS;
  unsigned short (*S)[136]  = (unsigned short (*)[136])BsS;

  const int tid   = threadIdx.x;
  const int mtile = blockIdx.x;
  const int row0  = mtile * 64;
  const float* zb = z + (size_t)(row0 >> 11) * NA * DA;    // T = 2048

  if (tid < 192) ((int*)idxs)[tid] = tbl[row0 * 3 + tid];
  __syncthreads();

  const int wv = tid >> 6, lane = tid & 63;
  const int q = lane >> 4, r16 = lane & 15;
  const int gr = tid >> 2, sub = tid & 3;

  f32x4 acc[4][8] = {};

  for (int k0 = 0; k0 < DA; k0 += 32) {
    // ---- stage A: gather-sum 3 z-rows, convert to bf16 ----
    {
      const float* p0 = zb + idxs[gr][0] * DA + k0 + sub * 8;
      const float* p1 = zb + idxs[gr][1] * DA + k0 + sub * 8;
      const float* p2 = zb + idxs[gr][2] * DA + k0 + sub * 8;
      float4 a0 = *(const float4*)p0, a1 = *(const float4*)(p0 + 4);
      float4 b0 = *(const float4*)p1, b1v = *(const float4*)(p1 + 4);
      float4 c0 = *(const float4*)p2, c1 = *(const float4*)(p2 + 4);
      float s[8];
      s[0] = a0.x + b0.x + c0.x;  s[1] = a0.y + b0.y + c0.y;
      s[2] = a0.z + b0.z + c0.z;  s[3] = a0.w + b0.w + c0.w;
      s[4] = a1.x + b1v.x + c1.x; s[5] = a1.y + b1v.y + c1.y;
      s[6] = a1.z + b1v.z + c1.z; s[7] = a1.w + b1v.w + c1.w;
      short8 pk;
#pragma unroll
      for (int j = 0; j < 8; j++) pk[j] = (short)f2bf(s[j]);
      *(short8*)&As[gr][sub * 8] = pk;
    }
    // ---- stage B: copy W1T[n][k0..k0+31] for all 512 n ----
    {
#pragma unroll
      for (int sdx = 0; sdx < 2; sdx++) {
        int n = tid + sdx * 256;
        const unsigned short* src = W1T + n * DA + k0;
#pragma unroll
        for (int i = 0; i < 4; i++)
          *(short8*)&Bs[n][i * 8] = *(const short8*)(src + i * 8);
      }
    }
    __syncthreads();

    bf16x8 afr[4], bfr[8];
#pragma unroll
    for (int mf = 0; mf < 4; mf++) afr[mf] = *(const bf16x8*)&As[mf * 16 + r16][q * 8];
#pragma unroll
    for (int nf = 0; nf < 8; nf++) bfr[nf] = *(const bf16x8*)&Bs[wv * 128 + nf * 16 + r16][q * 8];
#pragma unroll
    for (int mf = 0; mf < 4; mf++)
#pragma unroll
      for (int nf = 0; nf < 8; nf++)   // SWAPPED operands: C[row]=n-dim, C[col]=m-dim
        acc[mf][nf] = __builtin_amdgcn_mfma_f32_16x16x32_bf16(bfr[nf], afr[mf], acc[mf][nf], 0, 0, 0);
    __syncthreads();
  }

  // ---- bias + per-column partial stats ----
  // acc[mf][nf][p] = h[m = mf*16 + r16][n = wv*128 + nf*16 + q*4 + p]
#pragma unroll
  for (int nf = 0; nf < 8; nf++) {
#pragma unroll
    for (int p = 0; p < 4; p++) {
      const int n = wv * 128 + nf * 16 + q * 4 + p;
      const float bv = b1[n];
      float s1 = 0.f, s2 = 0.f;
#pragma unroll
      for (int mf = 0; mf < 4; mf++) {
        float v = acc[mf][nf][p] + bv;
        acc[mf][nf][p] = v;
        s1 += v; s2 += v * v;
      }
      s1 += __shfl_xor(s1, 1); s2 += __shfl_xor(s2, 1);
      s1 += __shfl_xor(s1, 2); s2 += __shfl_xor(s2, 2);
      s1 += __shfl_xor(s1, 4); s2 += __shfl_xor(s2, 4);
      s1 += __shfl_xor(s1, 8); s2 += __shfl_xor(s2, 8);
      if (r16 == 0) { psum[n * MT1 + mtile] = s1; psumsq[n * MT1 + mtile] = s2; }
    }
  }

  // ---- transpose-store h via LDS (4 chunks of 128 cols) ----
#pragma unroll 1
  for (int j = 0; j < 4; j++) {
    __syncthreads();                                  // S region free
#pragma unroll
    for (int mf = 0; mf < 4; mf++) {
#pragma unroll
      for (int f = 0; f < 2; f++) {
        const int nf = 2 * j + f;
        ushort4v v;
#pragma unroll
        for (int p = 0; p < 4; p++) v[p] = f2bf(acc[mf][nf][p]);
        *(ushort4v*)&S[mf * 16 + r16][wv * 32 + f * 16 + q * 4] = v;
      }
    }
    __syncthreads();
    const int r = tid >> 2, g = tid & 3;
    uint4* dst = (uint4*)&hbuf[(size_t)(row0 + r) * DH + g * 128 + j * 32];
#pragma unroll
    for (int i = 0; i < 4; i++)
      dst[i] = *(const uint4*)&S[r][g * 32 + i * 8];
  }
}

// ---------------------------------------------------------------------------
// k2: reduce partials -> affine coeffs  a = gamma*rsqrt(var+eps), d = beta - mean*a
// ---------------------------------------------------------------------------
__global__ void k2_stats(const float* __restrict__ psum, const float* __restrict__ psumsq,
                         const float* __restrict__ gamma, const float* __restrict__ beta,
                         float* __restrict__ coef) {
  const int col = blockIdx.x, lane = threadIdx.x;
  float s1 = 0.f, s2 = 0.f;
  for (int i = lane; i < MT1; i += 64) { s1 += psum[col * MT1 + i]; s2 += psumsq[col * MT1 + i]; }
#pragma unroll
  for (int d = 1; d < 64; d <<= 1) { s1 += __shfl_xor(s1, d); s2 += __shfl_xor(s2, d); }
  if (lane == 0) {
    const float inv = 1.0f / (float)M;
    float mean = s1 * inv;
    float var  = s2 * inv - mean * mean;
    float a = gamma[col] * rsqrtf(var + 1e-5f);
    coef[col]      = a;
    coef[DH + col] = beta[col] - mean * a;
  }
}

// ---------------------------------------------------------------------------
// k3: out = relu(h*a + d) @ W2 + b2
// grid: 1024 blocks (128-row tiles), 512 threads (8 waves = 2m x 4n);
// wave: 64 m x 64 n.  BK = 64.  A-frags loaded DIRECT from global (h row-major
// gives 16 B/lane, 64 B/row sectors), affine+relu applied in-register.
// ---------------------------------------------------------------------------
__global__ __launch_bounds__(512) void k3_gemm2(
    const unsigned short* __restrict__ hbuf, const unsigned short* __restrict__ W2T,
    const float* __restrict__ coef, const float* __restrict__ b2, float* __restrict__ out) {
  __shared__ __align__(16) unsigned short Bs[256][72];   // n x k-slice, +8 pad
  __shared__ float aC[DH], dC[DH];

  const int tid  = threadIdx.x;
  const int row0 = blockIdx.x * 128;

  aC[tid] = coef[tid];
  dC[tid] = coef[DH + tid];

  const int wv = tid >> 6, lane = tid & 63;
  const int q = lane >> 4, r16 = lane & 15;
  const int wm = wv >> 2, wn = wv & 3;

  f32x4 acc[4][4] = {};
  __syncthreads();

  for (int k0 = 0; k0 < DH; k0 += 64) {
    // ---- stage B: W2T[n][k0..k0+63] for all 256 n ----
#pragma unroll
    for (int i = 0; i < 4; i++) {
      int id = tid + i * 512;
      int n = id >> 3, c = id & 7;
      *(uint4*)&Bs[n][c * 8] = *(const uint4*)&W2T[n * DH + k0 + c * 8];
    }
    __syncthreads();

#pragma unroll
    for (int kc = 0; kc < 2; kc++) {
      const int kb = k0 + kc * 32 + q * 8;
      const float4 av0 = *(const float4*)&aC[kb];
      const float4 av1 = *(const float4*)&aC[kb + 4];
      const float4 dv0 = *(const float4*)&dC[kb];
      const float4 dv1 = *(const float4*)&dC[kb + 4];

      bf16x8 afr[4], bfr[4];
#pragma unroll
      for (int mf = 0; mf < 4; mf++) {
        bf16x8 hv = *(const bf16x8*)&hbuf[(size_t)(row0 + wm * 64 + mf * 16 + r16) * DH + kb];
        float f0 = fmaxf((float)hv[0] * av0.x + dv0.x, 0.f);
        float f1 = fmaxf((float)hv[1] * av0.y + dv0.y, 0.f);
        float f2 = fmaxf((float)hv[2] * av0.z + dv0.z, 0.f);
        float f3 = fmaxf((float)hv[3] * av0.w + dv0.w, 0.f);
        float f4 = fmaxf((float)hv[4] * av1.x + dv1.x, 0.f);
        float f5 = fmaxf((float)hv[5] * av1.y + dv1.y, 0.f);
        float f6 = fmaxf((float)hv[6] * av1.z + dv1.z, 0.f);
        float f7 = fmaxf((float)hv[7] * av1.w + dv1.w, 0.f);
        bf16x8 a;
        a[0] = (__bf16)f0; a[1] = (__bf16)f1; a[2] = (__bf16)f2; a[3] = (__bf16)f3;
        a[4] = (__bf16)f4; a[5] = (__bf16)f5; a[6] = (__bf16)f6; a[7] = (__bf16)f7;
        afr[mf] = a;
      }
#pragma unroll
      for (int nf = 0; nf < 4; nf++)
        bfr[nf] = *(const bf16x8*)&Bs[wn * 64 + nf * 16 + r16][kc * 32 + q * 8];
#pragma unroll
      for (int mf = 0; mf < 4; mf++)
#pragma unroll
        for (int nf = 0; nf < 4; nf++)
          acc[mf][nf] = __builtin_amdgcn_mfma_f32_16x16x32_bf16(afr[mf], bfr[nf], acc[mf][nf], 0, 0, 0);
    }
    __syncthreads();
  }

  // ---- epilogue: +b2, f32 store (64 B sectors per q-row) ----
#pragma unroll
  for (int nf = 0; nf < 4; nf++) {
    const int n = wn * 64 + nf * 16 + r16;
    const float bv = b2[n];
#pragma unroll
    for (int mf = 0; mf < 4; mf++) {
#pragma unroll
      for (int p = 0; p < 4; p++) {
        const int m = row0 + wm * 64 + mf * 16 + q * 4 + p;
        out[(size_t)m * DO + n] = acc[mf][nf][p] + bv;
      }
    }
  }
}

// ---------------------------------------------------------------------------
// workspace layout (bytes):
//   [0,256K)        W1T bf16 [512][256]
//   [256K,512K)     W2T bf16 [256][512]
//   [512K,516K)     coef f32 [1024] (a then d)
//   [1M,5M)         psum   f32 [512][2048]
//   [5M,9M)         psumsq f32 [512][2048]
//   [16M,144M)      h bf16 [131072][512]
// ---------------------------------------------------------------------------
extern "C" void kernel_launch(void* const* d_in, const int* in_sizes, int n_in,
                              void* d_out, int out_size, void* d_ws, size_t ws_size,
                              hipStream_t stream) {
  const float* z     = (const float*)d_in[0];
  const int*   tbl   = (const int*)d_in[1];
  const float* W1    = (const float*)d_in[2];
  const float* b1    = (const float*)d_in[3];
  const float* gamma = (const float*)d_in[4];
  const float* beta  = (const float*)d_in[5];
  const float* W2    = (const float*)d_in[6];
  const float* b2    = (const float*)d_in[7];
  float* out = (float*)d_out;

  char* ws = (char*)d_ws;
  unsigned short* W1T  = (unsigned short*)(ws);
  unsigned short* W2T  = (unsigned short*)(ws + (256 << 10));
  float*          coef = (float*)(ws + (512 << 10));
  float*          psum = (float*)(ws + (1 << 20));
  float*          psq  = (float*)(ws + (5 << 20));
  unsigned short* hbuf = (unsigned short*)(ws + (16 << 20));

  prep_kernel<<<512, 256, 0, stream>>>(W1, W2, W1T, W2T);
  k1_gemm1<<<MT1, 256, 0, stream>>>(z, tbl, W1T, b1, hbuf, psum, psq);
  k2_stats<<<DH, 64, 0, stream>>>(psum, psq, gamma, beta, coef);
  k3_gemm2<<<M / 128, 512, 0, stream>>>(hbuf, W2T, coef, b2, out);
}

// Round 3
// 518.634 us; speedup vs baseline: 2.3871x; 2.3871x over previous
//
#include <hip/hip_runtime.h>

// Problem constants
static constexpr int Bn  = 64;     // batch
static constexpr int T   = 2048;   // angles
static constexpr int NA  = 256;    // atoms
static constexpr int DA  = 256;    // d_atom (K1)
static constexpr int DH  = 512;    // d_hid  (N1 / K2)
static constexpr int DO  = 256;    // d_out  (N2)
static constexpr int M   = Bn * T;         // 131072 rows
static constexpr int MT1 = M / 64;         // 2048 m-tiles of 64 rows

typedef __attribute__((ext_vector_type(4))) float  f32x4;
typedef __attribute__((ext_vector_type(8))) __bf16 bf16x8;
typedef __attribute__((ext_vector_type(8))) short  short8;
typedef __attribute__((ext_vector_type(4))) unsigned short ushort4v;

__device__ __forceinline__ unsigned short f2bf(float f) {
  union { float f; unsigned u; } v; v.f = f;
  unsigned u = v.u + 0x7FFFu + ((v.u >> 16) & 1u);   // RNE
  return (unsigned short)(u >> 16);
}

// ---------------------------------------------------------------------------
// prep: W1 [256x512] f32 -> W1T [512][256] bf16 ; W2 [512x256] f32 -> W2T [256][512] bf16
// ---------------------------------------------------------------------------
__global__ void prep_kernel(const float* __restrict__ W1, const float* __restrict__ W2,
                            unsigned short* __restrict__ W1T, unsigned short* __restrict__ W2T) {
  int id = blockIdx.x * 256 + threadIdx.x;           // 131072 threads
  {
    int n = id >> 8, k = id & 255;                   // W1T[n][k] = W1[k][n]
    W1T[id] = f2bf(W1[k * DH + n]);
  }
  {
    int n = id >> 9, k = id & 511;                   // W2T[n][k] = W2[k][n]
    W2T[id] = f2bf(W2[k * DO + n]);
  }
}

// ---------------------------------------------------------------------------
// k1: gather(z,idx) -> x[64x256] (LDS, once) -> h = x@W1 + b1; B-frags direct
// from global (L2); NO barriers in K-loop; coalesced bf16 h-store via LDS
// transpose; per-column partial stats.
// grid: 2048 blocks, 256 threads (4 waves: each 64m x 128n).
// ---------------------------------------------------------------------------
__global__ __launch_bounds__(256) void k1_gemm1(
    const float* __restrict__ z, const int* __restrict__ tbl,
    const unsigned short* __restrict__ W1T, const float* __restrict__ b1,
    unsigned short* __restrict__ hbuf, float* __restrict__ psum, float* __restrict__ psumsq) {
  // As[64][264] (stride 264 ushorts: +8 pad, balanced banks); S[64][136] aliased on top
  __shared__ __align__(16) unsigned short AsS[64 * 264];
  __shared__ int idxs[64][3];
  unsigned short (*As)[264] = (unsigned short (*)[264])AsS;
  unsigned short (*S)[136]  = (unsigned short (*)[136])AsS;

  const int tid   = threadIdx.x;
  const int bid   = blockIdx.x;
  const int mtile = ((bid & 7) << 8) | (bid >> 3);   // XCD swizzle: XCD x -> batches [x*8,(x+1)*8)
  const int row0  = mtile * 64;
  const float* zb = z + (size_t)(row0 >> 11) * NA * DA;

  if (tid < 192) ((int*)idxs)[tid] = tbl[row0 * 3 + tid];
  __syncthreads();

  const int wv = tid >> 6, lane = tid & 63;
  const int q = lane >> 4, r16 = lane & 15;
  const int gr = tid >> 2, sub = tid & 3;

  // ---- full gather: x = z[a0]+z[a1]+z[a2] -> As (bf16), one barrier ----
  {
    const float* s0 = zb + idxs[gr][0] * DA;
    const float* s1 = zb + idxs[gr][1] * DA;
    const float* s2 = zb + idxs[gr][2] * DA;
#pragma unroll
    for (int c = 0; c < 8; c++) {
      const int col = c * 32 + sub * 8;
      float4 a0 = *(const float4*)(s0 + col), a1 = *(const float4*)(s0 + col + 4);
      float4 b0 = *(const float4*)(s1 + col), b1v = *(const float4*)(s1 + col + 4);
      float4 c0 = *(const float4*)(s2 + col), c1 = *(const float4*)(s2 + col + 4);
      short8 pk;
      pk[0] = (short)f2bf(a0.x + b0.x + c0.x);
      pk[1] = (short)f2bf(a0.y + b0.y + c0.y);
      pk[2] = (short)f2bf(a0.z + b0.z + c0.z);
      pk[3] = (short)f2bf(a0.w + b0.w + c0.w);
      pk[4] = (short)f2bf(a1.x + b1v.x + c1.x);
      pk[5] = (short)f2bf(a1.y + b1v.y + c1.y);
      pk[6] = (short)f2bf(a1.z + b1v.z + c1.z);
      pk[7] = (short)f2bf(a1.w + b1v.w + c1.w);
      *(short8*)&As[gr][col] = pk;
    }
  }
  __syncthreads();

  // ---- K-loop: no barriers; explicit 2-deep register double-buffer ----
  f32x4 acc[4][8] = {};
  const unsigned short* Wbase = W1T + (size_t)(wv * 128 + r16) * DA + q * 8;

  bf16x8 afr[2][4], bfr[2][8];
#pragma unroll
  for (int nf = 0; nf < 8; nf++) bfr[0][nf] = *(const bf16x8*)(Wbase + nf * 16 * DA);
#pragma unroll
  for (int mf = 0; mf < 4; mf++) afr[0][mf] = *(const bf16x8*)&As[mf * 16 + r16][q * 8];

#pragma unroll 2
  for (int c = 0; c < 8; c++) {
    const int cur = c & 1, nxt = cur ^ 1;
    if (c < 7) {
      const int k1o = (c + 1) * 32;
#pragma unroll
      for (int nf = 0; nf < 8; nf++) bfr[nxt][nf] = *(const bf16x8*)(Wbase + nf * 16 * DA + k1o);
#pragma unroll
      for (int mf = 0; mf < 4; mf++) afr[nxt][mf] = *(const bf16x8*)&As[mf * 16 + r16][k1o + q * 8];
    }
    // SWAPPED operands: C row(q*4+p) = n-sub, col(r16) = m-sub
#pragma unroll
    for (int mf = 0; mf < 4; mf++)
#pragma unroll
      for (int nf = 0; nf < 8; nf++)
        acc[mf][nf] = __builtin_amdgcn_mfma_f32_16x16x32_bf16(bfr[cur][nf], afr[cur][mf], acc[mf][nf], 0, 0, 0);
  }

  // ---- bias + per-column partial stats ----
  // acc[mf][nf][p] = h[m = mf*16 + r16][n = wv*128 + nf*16 + q*4 + p]
#pragma unroll
  for (int nf = 0; nf < 8; nf++) {
#pragma unroll
    for (int p = 0; p < 4; p++) {
      const int n = wv * 128 + nf * 16 + q * 4 + p;
      const float bv = b1[n];
      float s1 = 0.f, s2 = 0.f;
#pragma unroll
      for (int mf = 0; mf < 4; mf++) {
        float v = acc[mf][nf][p] + bv;
        acc[mf][nf][p] = v;
        s1 += v; s2 += v * v;
      }
      s1 += __shfl_xor(s1, 1); s2 += __shfl_xor(s2, 1);
      s1 += __shfl_xor(s1, 2); s2 += __shfl_xor(s2, 2);
      s1 += __shfl_xor(s1, 4); s2 += __shfl_xor(s2, 4);
      s1 += __shfl_xor(s1, 8); s2 += __shfl_xor(s2, 8);
      if (r16 == 0) { psum[n * MT1 + mtile] = s1; psumsq[n * MT1 + mtile] = s2; }
    }
  }

  // ---- transpose-store h via LDS: FULLY UNROLLED (static acc indices) ----
  const int r = tid >> 2, g = tid & 3;
#pragma unroll
  for (int j = 0; j < 4; j++) {
    __syncthreads();                                 // As/S region free for this chunk
#pragma unroll
    for (int mf = 0; mf < 4; mf++) {
#pragma unroll
      for (int f = 0; f < 2; f++) {
        ushort4v v;
#pragma unroll
        for (int p = 0; p < 4; p++) v[p] = f2bf(acc[mf][2 * j + f][p]);
        *(ushort4v*)&S[mf * 16 + r16][wv * 32 + f * 16 + q * 4] = v;
      }
    }
    __syncthreads();
    uint4* dst = (uint4*)&hbuf[(size_t)(row0 + r) * DH + g * 128 + j * 32];
    const uint4* src = (const uint4*)&S[r][g * 32];
    dst[0] = src[0]; dst[1] = src[1]; dst[2] = src[2]; dst[3] = src[3];
  }
}

// ---------------------------------------------------------------------------
// k2: reduce partials -> a = gamma*rsqrt(var+eps), d = beta - mean*a
// ---------------------------------------------------------------------------
__global__ void k2_stats(const float* __restrict__ psum, const float* __restrict__ psumsq,
                         const float* __restrict__ gamma, const float* __restrict__ beta,
                         float* __restrict__ coef) {
  const int col = blockIdx.x, lane = threadIdx.x;
  float s1 = 0.f, s2 = 0.f;
  for (int i = lane; i < MT1; i += 64) { s1 += psum[col * MT1 + i]; s2 += psumsq[col * MT1 + i]; }
#pragma unroll
  for (int d = 1; d < 64; d <<= 1) { s1 += __shfl_xor(s1, d); s2 += __shfl_xor(s2, d); }
  if (lane == 0) {
    const float inv = 1.0f / (float)M;
    float mean = s1 * inv;
    float var  = s2 * inv - mean * mean;
    float a = gamma[col] * rsqrtf(var + 1e-5f);
    coef[col]      = a;
    coef[DH + col] = beta[col] - mean * a;
  }
}

// ---------------------------------------------------------------------------
// k3: out = relu(h*a + d) @ W2 + b2.  NO LDS staging, NO K-loop barriers:
// A-frags direct from global h (row-major, 16B/lane full sectors), B-frags
// direct from global W2T (L2-resident).  grid: 2048 blocks, 256 threads
// (4 waves: each 64m x 64n), BK=32, 16 k-steps, reg double-buffer.
// ---------------------------------------------------------------------------
__global__ __launch_bounds__(256) void k3_gemm2(
    const unsigned short* __restrict__ hbuf, const unsigned short* __restrict__ W2T,
    const float* __restrict__ coef, const float* __restrict__ b2, float* __restrict__ out) {
  __shared__ float aC[DH], dC[DH];

  const int tid  = threadIdx.x;
  const int row0 = blockIdx.x * 64;

  aC[tid] = coef[tid];        aC[tid + 256] = coef[tid + 256];
  dC[tid] = coef[DH + tid];   dC[tid + 256] = coef[DH + 256 + tid];
  __syncthreads();

  const int wv = tid >> 6, lane = tid & 63;
  const int q = lane >> 4, r16 = lane & 15;

  f32x4 acc[4][4] = {};
  const unsigned short* hrow = hbuf + (size_t)(row0 + r16) * DH + q * 8;
  const unsigned short* wrow = W2T + (size_t)(wv * 64 + r16) * DH + q * 8;

  bf16x8 hbf[2][4], bfr[2][4];
#pragma unroll
  for (int mf = 0; mf < 4; mf++) hbf[0][mf] = *(const bf16x8*)(hrow + mf * 16 * DH);
#pragma unroll
  for (int nf = 0; nf < 4; nf++) bfr[0][nf] = *(const bf16x8*)(wrow + nf * 16 * DH);

#pragma unroll 2
  for (int c = 0; c < 16; c++) {
    const int cur = c & 1, nxt = cur ^ 1;
    if (c < 15) {
      const int k1o = (c + 1) * 32;
#pragma unroll
      for (int mf = 0; mf < 4; mf++) hbf[nxt][mf] = *(const bf16x8*)(hrow + mf * 16 * DH + k1o);
#pragma unroll
      for (int nf = 0; nf < 4; nf++) bfr[nxt][nf] = *(const bf16x8*)(wrow + nf * 16 * DH + k1o);
    }
    const int kb = c * 32 + q * 8;
    const float4 av0 = *(const float4*)&aC[kb];
    const float4 av1 = *(const float4*)&aC[kb + 4];
    const float4 dv0 = *(const float4*)&dC[kb];
    const float4 dv1 = *(const float4*)&dC[kb + 4];

    bf16x8 afr[4];
#pragma unroll
    for (int mf = 0; mf < 4; mf++) {
      bf16x8 hv = hbf[cur][mf];
      bf16x8 a;
      a[0] = (__bf16)fmaxf((float)hv[0] * av0.x + dv0.x, 0.f);
      a[1] = (__bf16)fmaxf((float)hv[1] * av0.y + dv0.y, 0.f);
      a[2] = (__bf16)fmaxf((float)hv[2] * av0.z + dv0.z, 0.f);
      a[3] = (__bf16)fmaxf((float)hv[3] * av0.w + dv0.w, 0.f);
      a[4] = (__bf16)fmaxf((float)hv[4] * av1.x + dv1.x, 0.f);
      a[5] = (__bf16)fmaxf((float)hv[5] * av1.y + dv1.y, 0.f);
      a[6] = (__bf16)fmaxf((float)hv[6] * av1.z + dv1.z, 0.f);
      a[7] = (__bf16)fmaxf((float)hv[7] * av1.w + dv1.w, 0.f);
      afr[mf] = a;
    }
#pragma unroll
    for (int mf = 0; mf < 4; mf++)
#pragma unroll
      for (int nf = 0; nf < 4; nf++)
        acc[mf][nf] = __builtin_amdgcn_mfma_f32_16x16x32_bf16(afr[mf], bfr[cur][nf], acc[mf][nf], 0, 0, 0);
  }

  // ---- epilogue: +b2, f32 stores (16 lanes x 4 B = 64 B full sectors) ----
#pragma unroll
  for (int nf = 0; nf < 4; nf++) {
    const int n = wv * 64 + nf * 16 + r16;
    const float bv = b2[n];
#pragma unroll
    for (int mf = 0; mf < 4; mf++) {
#pragma unroll
      for (int p = 0; p < 4; p++) {
        const int m = row0 + mf * 16 + q * 4 + p;
        out[(size_t)m * DO + n] = acc[mf][nf][p] + bv;
      }
    }
  }
}

// ---------------------------------------------------------------------------
// workspace layout (bytes):
//   [0,256K)        W1T bf16 [512][256]
//   [256K,512K)     W2T bf16 [256][512]
//   [512K,516K)     coef f32 [1024] (a then d)
//   [1M,5M)         psum   f32 [512][2048]
//   [5M,9M)         psumsq f32 [512][2048]
//   [16M,144M)      h bf16 [131072][512]
// ---------------------------------------------------------------------------
extern "C" void kernel_launch(void* const* d_in, const int* in_sizes, int n_in,
                              void* d_out, int out_size, void* d_ws, size_t ws_size,
                              hipStream_t stream) {
  const float* z     = (const float*)d_in[0];
  const int*   tbl   = (const int*)d_in[1];
  const float* W1    = (const float*)d_in[2];
  const float* b1    = (const float*)d_in[3];
  const float* gamma = (const float*)d_in[4];
  const float* beta  = (const float*)d_in[5];
  const float* W2    = (const float*)d_in[6];
  const float* b2    = (const float*)d_in[7];
  float* out = (float*)d_out;

  char* ws = (char*)d_ws;
  unsigned short* W1T  = (unsigned short*)(ws);
  unsigned short* W2T  = (unsigned short*)(ws + (256 << 10));
  float*          coef = (float*)(ws + (512 << 10));
  float*          psum = (float*)(ws + (1 << 20));
  float*          psq  = (float*)(ws + (5 << 20));
  unsigned short* hbuf = (unsigned short*)(ws + (16 << 20));

  prep_kernel<<<512, 256, 0, stream>>>(W1, W2, W1T, W2T);
  k1_gemm1<<<MT1, 256, 0, stream>>>(z, tbl, W1T, b1, hbuf, psum, psq);
  k2_stats<<<DH, 64, 0, stream>>>(psum, psq, gamma, beta, coef);
  k3_gemm2<<<M / 64, 256, 0, stream>>>(hbuf, W2T, coef, b2, out);
}